// Round 10
// baseline (191.853 us; speedup 1.0000x reference)
//
#include <hip/hip_runtime.h>
#include <stdint.h>

typedef _Float16 f16;
typedef _Float16 half8 __attribute__((ext_vector_type(8)));
typedef _Float16 half4 __attribute__((ext_vector_type(4)));
typedef _Float16 half2 __attribute__((ext_vector_type(2)));
typedef float floatx4 __attribute__((ext_vector_type(4)));

#define LOG2E 1.44269504088896340736f

// async global->LDS, 16B per lane. LDS dest must be wave-uniform base + lane*16.
__device__ __forceinline__ void async_cp16(const void* g, void* l) {
  __builtin_amdgcn_global_load_lds((const __attribute__((address_space(1))) void*)g,
                                   (__attribute__((address_space(3))) void*)l, 16, 0, 0);
}

// cvt_pkrtz returns __fp16x2; bit-cast to our _Float16-based half2.
__device__ __forceinline__ half2 pkrtz(float a, float b) {
  return __builtin_bit_cast(half2, __builtin_amdgcn_cvt_pkrtz(a, b));
}

// ---------------- fused prep: x transpose->fp16 + weight convert ----------------
__global__ __launch_bounds__(256) void k_prep(const float* __restrict__ x,
                                              f16* __restrict__ XT,
                                              const float* __restrict__ wqkv,
                                              const float* __restrict__ wproj,
                                              f16* __restrict__ WQ, f16* __restrict__ WP) {
  __shared__ f16 sT[64][72];
  const int bid = blockIdx.x;
  const int tid = threadIdx.x;
  if (bid < 576) {
    const int hw0 = (bid % 9) * 64, c0 = ((bid / 9) & 7) * 64, b = bid / 72;
    const int cc = tid >> 6, hwc = tid & 63;
    const float* xb = x + (size_t)b * 294912;
    for (int i = 0; i < 16; ++i) {
      int c = c0 + i * 4 + cc;
      sT[hwc][i * 4 + cc] = (f16)xb[c * 576 + hw0 + hwc];
    }
    __syncthreads();
    const int c_c = tid & 63, rr = tid >> 6;
    f16* xtb = XT + ((size_t)b * 576 + hw0) * 512 + c0;
    for (int j = 0; j < 16; ++j) {
      int r = j * 4 + rr;
      xtb[(size_t)r * 512 + c_c] = sT[r][c_c];
    }
  } else {
    const float SCALE_Q = 0.125f * LOG2E;
    const int total1 = 1536 * 512, total2 = 512 * 512;
    for (int idx = (bid - 576) * 256 + tid; idx < total1 + total2; idx += 128 * 256) {
      if (idx < total1) {
        int row = idx >> 9;
        float v = wqkv[idx];
        if ((row % 192) < 64) v *= SCALE_Q;
        WQ[idx] = (f16)v;
      } else {
        WP[idx - total1] = (f16)wproj[idx - total1];
      }
    }
  }
}

// ---------------- QKV GEMM: D[t][row] = XT[t][:] . WQ[row][:] ----------------
// Vh written KEY-INTERLEAVED within each 32-key group: position p = 2*(k&15) | (k>>4),
// so a 16B chunk c delivers keys {4c..4c+3} x {grp0,grp1} — the k-slot permutation
// consumed consistently by k_attn's PV 16x16x32 (A and B agree). Verified R6-R9.
__global__ __launch_bounds__(256) void k_qkv_gemm(const f16* __restrict__ XT,
                                                  const f16* __restrict__ WQ,
                                                  f16* __restrict__ Qh, f16* __restrict__ Kh,
                                                  f16* __restrict__ Vh) {
  const int t0 = blockIdx.x * 128, n0 = blockIdx.y * 128;
  __shared__ alignas(16) f16 smem[2 * 128 * 64];
  f16* sA = smem;
  f16* sB = smem + 128 * 64;
  const int tid = threadIdx.x;
  const int wave = tid >> 6, lane = tid & 63, quad = lane >> 4, l16 = lane & 15;
  const int msub = (wave & 1) * 64, nsub = (wave >> 1) * 64;
  const floatx4 fzero = {0.f, 0.f, 0.f, 0.f};
  floatx4 acc[4][4];
  for (int i = 0; i < 4; ++i)
    for (int j = 0; j < 4; ++j) acc[i][j] = fzero;

  for (int k0 = 0; k0 < 512; k0 += 64) {
    __syncthreads();
    for (int p = 0; p < 4; ++p) {
      int e = p * 256 + tid;
      int row = e >> 3, colb = e & 7;
      async_cp16((const char*)XT + ((size_t)(t0 + row) * 512 + k0 + colb * 8) * 2,
                 (char*)sA + e * 16);
      async_cp16((const char*)WQ + ((size_t)(n0 + row) * 512 + k0 + colb * 8) * 2,
                 (char*)sB + e * 16);
    }
    __syncthreads();
    for (int f = 0; f < 2; ++f) {
      half8 a[4], bfr[4];
      for (int ms = 0; ms < 4; ++ms)
        a[ms] = *(const half8*)&sA[(msub + ms * 16 + l16) * 64 + f * 32 + quad * 8];
      for (int ns = 0; ns < 4; ++ns)
        bfr[ns] = *(const half8*)&sB[(nsub + ns * 16 + l16) * 64 + f * 32 + quad * 8];
      for (int ms = 0; ms < 4; ++ms)
        for (int ns = 0; ns < 4; ++ns)
          acc[ms][ns] =
              __builtin_amdgcn_mfma_f32_16x16x32_f16(a[ms], bfr[ns], acc[ms][ns], 0, 0, 0);
    }
  }
  for (int ms = 0; ms < 4; ++ms) {
    int tbase = t0 + msub + ms * 16 + quad * 4;
    for (int ns = 0; ns < 4; ++ns) {
      int row = n0 + nsub + ns * 16 + l16;
      int h = row / 192, rr2 = row % 192;
      int sel = rr2 >> 6, d = rr2 & 63;
      if (sel == 2) continue;
      for (int r = 0; r < 4; ++r) {
        int t = tbase + r;
        int b = t / 576, hw = t % 576;
        int g = b >> 2, v = b & 3;
        int n = v * 576 + hw;
        int gh = g * 8 + h;
        f16 hv = (f16)acc[ms][ns][r];
        size_t idx = ((size_t)gh * 2304 + n) * 64 + d;
        if (sel == 0)
          Qh[idx] = hv;
        else
          Kh[idx] = hv;
      }
    }
  }
  const int r0 = n0 % 192;
  if (r0 != 0) {
    const int vloc = (r0 == 128) ? 0 : 64;
    const int h = (n0 + vloc) / 192;
    f16* sVT = smem;
    __syncthreads();
    if ((wave >> 1) == (vloc >> 6)) {
      for (int ms = 0; ms < 4; ++ms) {
        int tok = msub + ms * 16 + quad * 4;
        for (int ns = 0; ns < 4; ++ns) {
          int d = ns * 16 + l16;
          half4 hv;
          for (int r = 0; r < 4; ++r) hv[r] = (f16)acc[ms][ns][r];
          *(half4*)&sVT[d * 136 + tok] = hv;
        }
      }
    }
    __syncthreads();
    // interleaved V write: 32-token groups (576%32==0 -> no b-straddle)
    for (int pss = 0; pss < 4; ++pss) {
      int d = pss * 16 + (tid >> 4);
      int sub = tid & 15, gg = sub >> 2, u = sub & 3;
      int t = t0 + gg * 32;
      int b = t / 576, hw = t - b * 576;
      int gh = (b >> 2) * 8 + h, nb = (b & 3) * 576 + hw;
      half4 va = *(const half4*)&sVT[d * 136 + gg * 32 + u * 4];
      half4 vb2 = *(const half4*)&sVT[d * 136 + gg * 32 + 16 + u * 4];
      half8 w = __builtin_shufflevector(va, vb2, 0, 4, 1, 5, 2, 6, 3, 7);
      *(half8*)(Vh + (size_t)gh * 147456 + (size_t)d * 2304 + nb + u * 8) = w;
    }
  }
}

// ---------------- flash attention: 48 queries/block, 6 waves, key-split 2-way ----
// grid = 48 x 16 = 768 blocks = exactly 3/CU, 18 waves/CU (requires VGPR <= 64!).
// V: LDS-staged interleaved (R8/R9-verified). K: DIRECT GLOBAL to registers with
// cross-iteration prefetch — K rows are 128B-dense (16 whole lines/instr, L1-reused
// by the 3 qgrp waves), unlike V's stride-4608 pattern that failed in R6. kreg(kt)
// is consumed by QK then immediately reloaded with K(kt+1); the loads hide under
// softmax+PV+barrier+V-stage. LDS halves to 16 KB -> per-CU LDS-read floor halves.
__global__ __launch_bounds__(384, 4) void k_attn(const f16* __restrict__ Qh,
                                                 const f16* __restrict__ Kh,
                                                 const f16* __restrict__ Vh,
                                                 f16* __restrict__ AOT) {
  const int mt = blockIdx.x, gh = blockIdx.y;
  const int m0 = mt * 48;
  const int g = gh >> 3, h = gh & 7;
  const f16* Qg = Qh + (size_t)gh * 147456;  // [n][d]
  const f16* Kg = Kh + (size_t)gh * 147456;  // [n][d]
  const f16* Vg = Vh + (size_t)gh * 147456;  // [d][n'] key-interleaved
  __shared__ alignas(16) f16 smem[8192];     // 16 KB: sV[2 str][2 buf][64*32]
  f16* sV = smem;
  const int tid = threadIdx.x;
  const int wave = tid >> 6, lane = tid & 63, quad = lane >> 4, l16 = lane & 15;
  const int str = wave & 1, qgrp = wave >> 1;
  const floatx4 fzero = {0.f, 0.f, 0.f, 0.f};
  const int vsw = (l16 >> 1) & 3;
  const half2 one2 = {(f16)1.f, (f16)1.f};

  // stage 32-key V tiles for both streams (512 cp16 units over 384 threads).
  // V tile [64 d][32 key interleaved]: 64B rows, source pre-swizzle pc ^ ((row>>1)&3);
  // read side applies the same XOR -> cancels (both-sides rule). R8/R9-verified.
  auto stage_v = [&](int ktile, int buf) {
#pragma unroll
    for (int p = 0; p < 2; ++p) {
      int idx = p * 384 + tid;
      if (idx < 512) {
        int st = idx >> 8, unit = idx & 255;
        int row = unit >> 2, pc = unit & 3;
        async_cp16(Vg + (size_t)row * 2304 + st * 1152 + ktile * 32 +
                       ((pc ^ ((row >> 1) & 3)) << 3),
                   (char*)(sV + (st * 2 + buf) * 2048) + unit * 16);
      }
    }
  };

  // K fragment loads, dense global: rows (nt*16+l16), d = quad*8 / 32+quad*8
  const f16* Kbase = Kg + (size_t)str * 1152 * 64;
  half8 kreg[4];  // [nt][half]
  auto loadK = [&](int kt) {
    const f16* kp = Kbase + (size_t)kt * 32 * 64;
#pragma unroll
    for (int nt = 0; nt < 2; ++nt) {
      kreg[nt * 2 + 0] = *(const half8*)(kp + (size_t)(nt * 16 + l16) * 64 + quad * 8);
      kreg[nt * 2 + 1] = *(const half8*)(kp + (size_t)(nt * 16 + l16) * 64 + 32 + quad * 8);
    }
  };

  // Q direct to registers (B-frag: col=l16, k=quad*8+j / +32)
  half8 qa[2];
  {
    int qrow = m0 + qgrp * 16 + l16;
    qa[0] = *(const half8*)(Qg + (size_t)qrow * 64 + quad * 8);
    qa[1] = *(const half8*)(Qg + (size_t)qrow * 64 + 32 + quad * 8);
  }

  stage_v(0, 0);
  loadK(0);
  __syncthreads();
  stage_v(1, 1);

  float l_lane = 0.f;
  floatx4 o[4];
  for (int dt = 0; dt < 4; ++dt) o[dt] = fzero;

  for (int kt = 0; kt < 36; ++kt) {
    const f16* bV = sV + (str * 2 + (kt & 1)) * 2048;

    // QK for both 16-key halves from registers
    floatx4 ta, tb;
    ta = __builtin_amdgcn_mfma_f32_16x16x32_f16(kreg[0], qa[0], fzero, 0, 0, 0);
    ta = __builtin_amdgcn_mfma_f32_16x16x32_f16(kreg[1], qa[1], ta, 0, 0, 0);
    tb = __builtin_amdgcn_mfma_f32_16x16x32_f16(kreg[2], qa[0], fzero, 0, 0, 0);
    tb = __builtin_amdgcn_mfma_f32_16x16x32_f16(kreg[3], qa[1], tb, 0, 0, 0);

    // prefetch K(kt+1): issued now, consumed next iteration (covers L1/L2 latency)
    if (kt < 35) loadK(kt + 1);

    half2 a0 = pkrtz(__builtin_amdgcn_exp2f(ta[0]), __builtin_amdgcn_exp2f(ta[1]));
    half2 a1 = pkrtz(__builtin_amdgcn_exp2f(ta[2]), __builtin_amdgcn_exp2f(ta[3]));
    half2 b0 = pkrtz(__builtin_amdgcn_exp2f(tb[0]), __builtin_amdgcn_exp2f(tb[1]));
    half2 b1 = pkrtz(__builtin_amdgcn_exp2f(tb[2]), __builtin_amdgcn_exp2f(tb[3]));
    l_lane = __builtin_amdgcn_fdot2(a0, one2, l_lane, false);
    l_lane = __builtin_amdgcn_fdot2(a1, one2, l_lane, false);
    l_lane = __builtin_amdgcn_fdot2(b0, one2, l_lane, false);
    l_lane = __builtin_amdgcn_fdot2(b1, one2, l_lane, false);
    half4 pa = __builtin_shufflevector(a0, a1, 0, 1, 2, 3);
    half4 pb = __builtin_shufflevector(b0, b1, 0, 1, 2, 3);
    half8 pf = __builtin_shufflevector(pa, pb, 0, 4, 1, 5, 2, 6, 3, 7);

#pragma unroll
    for (int dt = 0; dt < 4; ++dt) {
      half8 vb = *(const half8*)&bV[(dt * 16 + l16) * 32 + ((quad ^ vsw) << 3)];
      o[dt] = __builtin_amdgcn_mfma_f32_16x16x32_f16(pf, vb, o[dt], 0, 0, 0);
    }

    if (kt < 35) {
      __syncthreads();
      if (kt + 2 < 36) stage_v(kt + 2, kt & 1);
    }
  }

  // 2-way combine via LDS (reuse smem 16 KB: cO 12 KB + cL 768 B)
  __syncthreads();
  float* cO = (float*)smem;                   // [qgrp][dt][lane][4]
  float* cL = (float*)((char*)smem + 12288);  // [qgrp][lane]
  if (str == 1) {
    cL[qgrp * 64 + lane] = l_lane;
#pragma unroll
    for (int dt = 0; dt < 4; ++dt)
      *(floatx4*)&cO[((qgrp * 4 + dt) * 64 + lane) * 4] = o[dt];
  }
  __syncthreads();
  if (str == 0) {
    l_lane += cL[qgrp * 64 + lane];
#pragma unroll
    for (int dt = 0; dt < 4; ++dt)
      o[dt] += *(const floatx4*)&cO[((qgrp * 4 + dt) * 64 + lane) * 4];

    l_lane += __shfl_xor(l_lane, 16, 64);
    l_lane += __shfl_xor(l_lane, 32, 64);
    float inv[4];
#pragma unroll
    for (int r = 0; r < 4; ++r) {
      float lr = __shfl(l_lane, quad * 4 + r, 64);
      inv[r] = 1.f / lr;
    }
#pragma unroll
    for (int dt = 0; dt < 4; ++dt)
#pragma unroll
      for (int r = 0; r < 4; ++r) {
        int n_tok = m0 + qgrp * 16 + quad * 4 + r;
        int v = n_tok / 576, hw = n_tok % 576;
        int bb = g * 4 + v;
        int c = h * 64 + dt * 16 + l16;
        AOT[((size_t)bb * 576 + hw) * 512 + c] = (f16)(o[dt][r] * inv[r]);
      }
  }
}

// ---------------- proj GEMM: 64(o) x 128(t) tiles, grid 288 blocks ----------------
__global__ __launch_bounds__(256) void k_proj_gemm(const f16* __restrict__ AOT,
                                                   const f16* __restrict__ WP,
                                                   const float* __restrict__ bias,
                                                   float* __restrict__ out) {
  const int o0 = blockIdx.x * 64, t0 = blockIdx.y * 128;
  __shared__ alignas(16) f16 sA[64 * 64];   // [o][k]
  __shared__ alignas(16) f16 sB[128 * 64];  // [token][k]
  const int tid = threadIdx.x;
  const int wave = tid >> 6, lane = tid & 63, quad = lane >> 4, l16 = lane & 15;
  const int msub = (wave & 1) * 32, nsub = (wave >> 1) * 64;
  const floatx4 fzero = {0.f, 0.f, 0.f, 0.f};
  floatx4 acc[2][4];
  for (int i = 0; i < 2; ++i)
    for (int j = 0; j < 4; ++j) acc[i][j] = fzero;

  for (int k0 = 0; k0 < 512; k0 += 64) {
    __syncthreads();
    for (int p = 0; p < 2; ++p) {
      int e = p * 256 + tid;
      int row = e >> 3, colb = e & 7;
      async_cp16((const char*)WP + ((size_t)(o0 + row) * 512 + k0 + colb * 8) * 2,
                 (char*)sA + e * 16);
    }
    for (int p = 0; p < 4; ++p) {
      int e = p * 256 + tid;
      int row = e >> 3, colb = e & 7;
      async_cp16((const char*)AOT + ((size_t)(t0 + row) * 512 + k0 + colb * 8) * 2,
                 (char*)sB + e * 16);
    }
    __syncthreads();
    for (int f = 0; f < 2; ++f) {
      half8 a[2], bfr[4];
      for (int ms = 0; ms < 2; ++ms)
        a[ms] = *(const half8*)&sA[(msub + ms * 16 + l16) * 64 + f * 32 + quad * 8];
      for (int ns = 0; ns < 4; ++ns)
        bfr[ns] = *(const half8*)&sB[(nsub + ns * 16 + l16) * 64 + f * 32 + quad * 8];
      for (int ms = 0; ms < 2; ++ms)
        for (int ns = 0; ns < 4; ++ns)
          acc[ms][ns] =
              __builtin_amdgcn_mfma_f32_16x16x32_f16(a[ms], bfr[ns], acc[ms][ns], 0, 0, 0);
    }
  }
  for (int ms = 0; ms < 2; ++ms) {
    int o_row = o0 + msub + ms * 16 + quad * 4;
    for (int ns = 0; ns < 4; ++ns) {
      int t = t0 + nsub + ns * 16 + l16;
      int b = t / 576, hw = t % 576;
      for (int r = 0; r < 4; ++r) {
        int orow = o_row + r;
        out[(size_t)b * 294912 + (size_t)orow * 576 + hw] = acc[ms][ns][r] + bias[orow];
      }
    }
  }
}

extern "C" void kernel_launch(void* const* d_in, const int* in_sizes, int n_in,
                              void* d_out, int out_size, void* d_ws, size_t ws_size,
                              hipStream_t stream) {
  const float* x = (const float*)d_in[0];
  const float* wqkv = (const float*)d_in[1];
  const float* wproj = (const float*)d_in[2];
  const float* bias = (const float*)d_in[3];
  float* out = (float*)d_out;
  char* ws = (char*)d_ws;
  f16* XT = (f16*)(ws + 0);          // 4,718,592
  f16* WQ = (f16*)(ws + 4718592);    // 1,572,864
  f16* WP = (f16*)(ws + 6291456);    //   524,288
  f16* Qh = (f16*)(ws + 6815744);    // 4,718,592
  f16* Kh = (f16*)(ws + 11534336);   // 4,718,592
  f16* Vh = (f16*)(ws + 16252928);   // 4,718,592  ([gh][d][n'] key-interleaved)
  f16* AOT = (f16*)(ws + 20971520);  // 4,718,592

  k_prep<<<dim3(704), dim3(256), 0, stream>>>(x, XT, wqkv, wproj, WQ, WP);
  k_qkv_gemm<<<dim3(36, 12), dim3(256), 0, stream>>>(XT, WQ, Qh, Kh, Vh);
  k_attn<<<dim3(48, 16), dim3(384), 0, stream>>>(Qh, Kh, Vh, AOT);
  k_proj_gemm<<<dim3(8, 36), dim3(256), 0, stream>>>(AOT, WP, bias, out);
}

// Round 11
// 141.524 us; speedup vs baseline: 1.3556x; 1.3556x over previous
//
#include <hip/hip_runtime.h>
#include <stdint.h>

typedef _Float16 f16;
typedef _Float16 half8 __attribute__((ext_vector_type(8)));
typedef _Float16 half4 __attribute__((ext_vector_type(4)));
typedef _Float16 half2 __attribute__((ext_vector_type(2)));
typedef float floatx4 __attribute__((ext_vector_type(4)));

#define LOG2E 1.44269504088896340736f

// async global->LDS, 16B per lane. LDS dest must be wave-uniform base + lane*16.
__device__ __forceinline__ void async_cp16(const void* g, void* l) {
  __builtin_amdgcn_global_load_lds((const __attribute__((address_space(1))) void*)g,
                                   (__attribute__((address_space(3))) void*)l, 16, 0, 0);
}

// cvt_pkrtz returns __fp16x2; bit-cast to our _Float16-based half2.
__device__ __forceinline__ half2 pkrtz(float a, float b) {
  return __builtin_bit_cast(half2, __builtin_amdgcn_cvt_pkrtz(a, b));
}

// ---------------- fused prep: x transpose->fp16 + weight convert ----------------
__global__ __launch_bounds__(256) void k_prep(const float* __restrict__ x,
                                              f16* __restrict__ XT,
                                              const float* __restrict__ wqkv,
                                              const float* __restrict__ wproj,
                                              f16* __restrict__ WQ, f16* __restrict__ WP) {
  __shared__ f16 sT[64][72];
  const int bid = blockIdx.x;
  const int tid = threadIdx.x;
  if (bid < 576) {
    const int hw0 = (bid % 9) * 64, c0 = ((bid / 9) & 7) * 64, b = bid / 72;
    const int cc = tid >> 6, hwc = tid & 63;
    const float* xb = x + (size_t)b * 294912;
    for (int i = 0; i < 16; ++i) {
      int c = c0 + i * 4 + cc;
      sT[hwc][i * 4 + cc] = (f16)xb[c * 576 + hw0 + hwc];
    }
    __syncthreads();
    const int c_c = tid & 63, rr = tid >> 6;
    f16* xtb = XT + ((size_t)b * 576 + hw0) * 512 + c0;
    for (int j = 0; j < 16; ++j) {
      int r = j * 4 + rr;
      xtb[(size_t)r * 512 + c_c] = sT[r][c_c];
    }
  } else {
    const float SCALE_Q = 0.125f * LOG2E;
    const int total1 = 1536 * 512, total2 = 512 * 512;
    for (int idx = (bid - 576) * 256 + tid; idx < total1 + total2; idx += 128 * 256) {
      if (idx < total1) {
        int row = idx >> 9;
        float v = wqkv[idx];
        if ((row % 192) < 64) v *= SCALE_Q;
        WQ[idx] = (f16)v;
      } else {
        WP[idx - total1] = (f16)wproj[idx - total1];
      }
    }
  }
}

// ---------------- QKV GEMM: D[t][row] = XT[t][:] . WQ[row][:] ----------------
// Double-buffered k-loop: stage(next) issued BEFORE compute(cur); one barrier/iter,
// so the pre-barrier vmcnt(0) drain lands after a full compute phase (attn-R3
// verified pattern). Vh written KEY-INTERLEAVED within each 32-key group:
// position p = 2*(k&15) | (k>>4) — consumed by k_attn's PV 16x16x32 (R6-R9 verified).
__global__ __launch_bounds__(256) void k_qkv_gemm(const f16* __restrict__ XT,
                                                  const f16* __restrict__ WQ,
                                                  f16* __restrict__ Qh, f16* __restrict__ Kh,
                                                  f16* __restrict__ Vh) {
  const int t0 = blockIdx.x * 128, n0 = blockIdx.y * 128;
  __shared__ alignas(16) f16 smem[2 * 16384];  // 64 KB: [buf][A 8192 | B 8192]
  const int tid = threadIdx.x;
  const int wave = tid >> 6, lane = tid & 63, quad = lane >> 4, l16 = lane & 15;
  const int msub = (wave & 1) * 64, nsub = (wave >> 1) * 64;
  const floatx4 fzero = {0.f, 0.f, 0.f, 0.f};
  floatx4 acc[4][4];
  for (int i = 0; i < 4; ++i)
    for (int j = 0; j < 4; ++j) acc[i][j] = fzero;

  auto stage = [&](int buf, int k0) {
    f16* dA = smem + buf * 16384;
    f16* dB = dA + 8192;
#pragma unroll
    for (int p = 0; p < 4; ++p) {
      int e = p * 256 + tid;
      int row = e >> 3, colb = e & 7;
      async_cp16((const char*)XT + ((size_t)(t0 + row) * 512 + k0 + colb * 8) * 2,
                 (char*)dA + e * 16);
      async_cp16((const char*)WQ + ((size_t)(n0 + row) * 512 + k0 + colb * 8) * 2,
                 (char*)dB + e * 16);
    }
  };

  stage(0, 0);
  __syncthreads();
  for (int it = 0; it < 8; ++it) {
    int cur = it & 1;
    if (it < 7) stage(cur ^ 1, (it + 1) * 64);
    const f16* sA = smem + cur * 16384;
    const f16* sB = sA + 8192;
    for (int f = 0; f < 2; ++f) {
      half8 a[4], bfr[4];
      for (int ms = 0; ms < 4; ++ms)
        a[ms] = *(const half8*)&sA[(msub + ms * 16 + l16) * 64 + f * 32 + quad * 8];
      for (int ns = 0; ns < 4; ++ns)
        bfr[ns] = *(const half8*)&sB[(nsub + ns * 16 + l16) * 64 + f * 32 + quad * 8];
      for (int ms = 0; ms < 4; ++ms)
        for (int ns = 0; ns < 4; ++ns)
          acc[ms][ns] =
              __builtin_amdgcn_mfma_f32_16x16x32_f16(a[ms], bfr[ns], acc[ms][ns], 0, 0, 0);
    }
    __syncthreads();
  }
  for (int ms = 0; ms < 4; ++ms) {
    int tbase = t0 + msub + ms * 16 + quad * 4;
    for (int ns = 0; ns < 4; ++ns) {
      int row = n0 + nsub + ns * 16 + l16;
      int h = row / 192, rr2 = row % 192;
      int sel = rr2 >> 6, d = rr2 & 63;
      if (sel == 2) continue;
      for (int r = 0; r < 4; ++r) {
        int t = tbase + r;
        int b = t / 576, hw = t % 576;
        int g = b >> 2, v = b & 3;
        int n = v * 576 + hw;
        int gh = g * 8 + h;
        f16 hv = (f16)acc[ms][ns][r];
        size_t idx = ((size_t)gh * 2304 + n) * 64 + d;
        if (sel == 0)
          Qh[idx] = hv;
        else
          Kh[idx] = hv;
      }
    }
  }
  const int r0 = n0 % 192;
  if (r0 != 0) {
    const int vloc = (r0 == 128) ? 0 : 64;
    const int h = (n0 + vloc) / 192;
    f16* sVT = smem;
    __syncthreads();
    if ((wave >> 1) == (vloc >> 6)) {
      for (int ms = 0; ms < 4; ++ms) {
        int tok = msub + ms * 16 + quad * 4;
        for (int ns = 0; ns < 4; ++ns) {
          int d = ns * 16 + l16;
          half4 hv;
          for (int r = 0; r < 4; ++r) hv[r] = (f16)acc[ms][ns][r];
          *(half4*)&sVT[d * 136 + tok] = hv;
        }
      }
    }
    __syncthreads();
    // interleaved V write: 32-token groups (576%32==0 -> no b-straddle)
    for (int pss = 0; pss < 4; ++pss) {
      int d = pss * 16 + (tid >> 4);
      int sub = tid & 15, gg = sub >> 2, u = sub & 3;
      int t = t0 + gg * 32;
      int b = t / 576, hw = t - b * 576;
      int gh = (b >> 2) * 8 + h, nb = (b & 3) * 576 + hw;
      half4 va = *(const half4*)&sVT[d * 136 + gg * 32 + u * 4];
      half4 vb2 = *(const half4*)&sVT[d * 136 + gg * 32 + 16 + u * 4];
      half8 w = __builtin_shufflevector(va, vb2, 0, 4, 1, 5, 2, 6, 3, 7);
      *(half8*)(Vh + (size_t)gh * 147456 + (size_t)d * 2304 + nb + u * 8) = w;
    }
  }
}

// ---------------- flash attention: R9-verified design, unchanged ----------------
// 48 queries/block, 6 waves, key-split 2-way; grid 768 = exactly 3/CU.
// K LDS-staged swizzled; V LDS-staged interleaved; PV one mfma 16x16x32 per dt.
// (R6/R7/R10 established: vector global loads in this loop => ~91 us. Staged only.)
__global__ __launch_bounds__(384, 4) void k_attn(const f16* __restrict__ Qh,
                                                 const f16* __restrict__ Kh,
                                                 const f16* __restrict__ Vh,
                                                 f16* __restrict__ AOT) {
  const int mt = blockIdx.x, gh = blockIdx.y;
  const int m0 = mt * 48;
  const int g = gh >> 3, h = gh & 7;
  const f16* Qg = Qh + (size_t)gh * 147456;  // [n][d]
  const f16* Kg = Kh + (size_t)gh * 147456;  // [n][d]
  const f16* Vg = Vh + (size_t)gh * 147456;  // [d][n'] key-interleaved
  __shared__ alignas(16) f16 smem[16384];    // 32 KB
  f16* sK = smem;                            // [str 2][buf 2][32*64]
  f16* sV = smem + 8192;                     // [str 2][buf 2][64*32]
  const int tid = threadIdx.x;
  const int wave = tid >> 6, lane = tid & 63, quad = lane >> 4, l16 = lane & 15;
  const int str = wave & 1, qgrp = wave >> 1;
  const floatx4 fzero = {0.f, 0.f, 0.f, 0.f};
  const int sw = l16 & 7;
  const int vsw = (l16 >> 1) & 3;
  const half2 one2 = {(f16)1.f, (f16)1.f};

  auto stage_kv = [&](int ktile, int buf) {
#pragma unroll
    for (int p = 0; p < 3; ++p) {
      int idx = p * 384 + tid;
      if (idx < 1024) {
        int isV = idx >= 512;
        int rem = idx & 511;
        int st = rem >> 8, unit = rem & 255;
        if (!isV) {
          int row = unit >> 3, cb = unit & 7;
          async_cp16(
              Kg + (size_t)(st * 1152 + ktile * 32 + row) * 64 + ((cb ^ (row & 7)) << 3),
              (char*)(sK + (st * 2 + buf) * 2048) + unit * 16);
        } else {
          int row = unit >> 2, pc = unit & 3;
          async_cp16(Vg + (size_t)row * 2304 + st * 1152 + ktile * 32 +
                         ((pc ^ ((row >> 1) & 3)) << 3),
                     (char*)(sV + (st * 2 + buf) * 2048) + unit * 16);
        }
      }
    }
  };

  half8 qa[2];
  {
    int qrow = m0 + qgrp * 16 + l16;
    qa[0] = *(const half8*)(Qg + (size_t)qrow * 64 + quad * 8);
    qa[1] = *(const half8*)(Qg + (size_t)qrow * 64 + 32 + quad * 8);
  }

  stage_kv(0, 0);
  __syncthreads();
  stage_kv(1, 1);

  float l_lane = 0.f;
  floatx4 o[4];
  for (int dt = 0; dt < 4; ++dt) o[dt] = fzero;

  for (int kt = 0; kt < 36; ++kt) {
    const f16* bK = sK + (str * 2 + (kt & 1)) * 2048;
    const f16* bV = sV + (str * 2 + (kt & 1)) * 2048;

    half8 vb[4];
#pragma unroll
    for (int dt = 0; dt < 4; ++dt)
      vb[dt] = *(const half8*)&bV[(dt * 16 + l16) * 32 + ((quad ^ vsw) << 3)];

    floatx4 ta, tb;
    {
      half8 k0 = *(const half8*)&bK[l16 * 64 + ((quad ^ sw) << 3)];
      half8 k1 = *(const half8*)&bK[l16 * 64 + (((4 + quad) ^ sw) << 3)];
      ta = __builtin_amdgcn_mfma_f32_16x16x32_f16(k0, qa[0], fzero, 0, 0, 0);
      ta = __builtin_amdgcn_mfma_f32_16x16x32_f16(k1, qa[1], ta, 0, 0, 0);
    }
    {
      half8 k0 = *(const half8*)&bK[(16 + l16) * 64 + ((quad ^ sw) << 3)];
      half8 k1 = *(const half8*)&bK[(16 + l16) * 64 + (((4 + quad) ^ sw) << 3)];
      tb = __builtin_amdgcn_mfma_f32_16x16x32_f16(k0, qa[0], fzero, 0, 0, 0);
      tb = __builtin_amdgcn_mfma_f32_16x16x32_f16(k1, qa[1], tb, 0, 0, 0);
    }
    half2 a0 = pkrtz(__builtin_amdgcn_exp2f(ta[0]), __builtin_amdgcn_exp2f(ta[1]));
    half2 a1 = pkrtz(__builtin_amdgcn_exp2f(ta[2]), __builtin_amdgcn_exp2f(ta[3]));
    half2 b0 = pkrtz(__builtin_amdgcn_exp2f(tb[0]), __builtin_amdgcn_exp2f(tb[1]));
    half2 b1 = pkrtz(__builtin_amdgcn_exp2f(tb[2]), __builtin_amdgcn_exp2f(tb[3]));
    l_lane = __builtin_amdgcn_fdot2(a0, one2, l_lane, false);
    l_lane = __builtin_amdgcn_fdot2(a1, one2, l_lane, false);
    l_lane = __builtin_amdgcn_fdot2(b0, one2, l_lane, false);
    l_lane = __builtin_amdgcn_fdot2(b1, one2, l_lane, false);
    half4 pa = __builtin_shufflevector(a0, a1, 0, 1, 2, 3);
    half4 pb = __builtin_shufflevector(b0, b1, 0, 1, 2, 3);
    half8 pf = __builtin_shufflevector(pa, pb, 0, 4, 1, 5, 2, 6, 3, 7);

#pragma unroll
    for (int dt = 0; dt < 4; ++dt)
      o[dt] = __builtin_amdgcn_mfma_f32_16x16x32_f16(pf, vb[dt], o[dt], 0, 0, 0);

    if (kt < 35) {
      __syncthreads();
      if (kt + 2 < 36) stage_kv(kt + 2, kt & 1);
    }
  }

  __syncthreads();
  float* cO = (float*)smem;                   // [qgrp][dt][lane][4]
  float* cL = (float*)((char*)smem + 24576);  // [qgrp][lane]
  if (str == 1) {
    cL[qgrp * 64 + lane] = l_lane;
#pragma unroll
    for (int dt = 0; dt < 4; ++dt)
      *(floatx4*)&cO[((qgrp * 4 + dt) * 64 + lane) * 4] = o[dt];
  }
  __syncthreads();
  if (str == 0) {
    l_lane += cL[qgrp * 64 + lane];
#pragma unroll
    for (int dt = 0; dt < 4; ++dt)
      o[dt] += *(const floatx4*)&cO[((qgrp * 4 + dt) * 64 + lane) * 4];

    l_lane += __shfl_xor(l_lane, 16, 64);
    l_lane += __shfl_xor(l_lane, 32, 64);
    float inv[4];
#pragma unroll
    for (int r = 0; r < 4; ++r) {
      float lr = __shfl(l_lane, quad * 4 + r, 64);
      inv[r] = 1.f / lr;
    }
#pragma unroll
    for (int dt = 0; dt < 4; ++dt)
#pragma unroll
      for (int r = 0; r < 4; ++r) {
        int n_tok = m0 + qgrp * 16 + quad * 4 + r;
        int v = n_tok / 576, hw = n_tok % 576;
        int bb = g * 4 + v;
        int c = h * 64 + dt * 16 + l16;
        AOT[((size_t)bb * 576 + hw) * 512 + c] = (f16)(o[dt][r] * inv[r]);
      }
  }
}

// ---------------- proj GEMM: 64(o) x 128(t) tiles, double-buffered k-loop ----------
__global__ __launch_bounds__(256) void k_proj_gemm(const f16* __restrict__ AOT,
                                                   const f16* __restrict__ WP,
                                                   const float* __restrict__ bias,
                                                   float* __restrict__ out) {
  const int o0 = blockIdx.x * 64, t0 = blockIdx.y * 128;
  __shared__ alignas(16) f16 smem[2 * 12288];  // 48 KB: [buf][A 4096 | B 8192]
  const int tid = threadIdx.x;
  const int wave = tid >> 6, lane = tid & 63, quad = lane >> 4, l16 = lane & 15;
  const int msub = (wave & 1) * 32, nsub = (wave >> 1) * 64;
  const floatx4 fzero = {0.f, 0.f, 0.f, 0.f};
  floatx4 acc[2][4];
  for (int i = 0; i < 2; ++i)
    for (int j = 0; j < 4; ++j) acc[i][j] = fzero;

  auto stage = [&](int buf, int k0) {
    f16* dA = smem + buf * 12288;
    f16* dB = dA + 4096;
#pragma unroll
    for (int p = 0; p < 2; ++p) {
      int e = p * 256 + tid;
      int row = e >> 3, colb = e & 7;
      async_cp16((const char*)WP + ((size_t)(o0 + row) * 512 + k0 + colb * 8) * 2,
                 (char*)dA + e * 16);
    }
#pragma unroll
    for (int p = 0; p < 4; ++p) {
      int e = p * 256 + tid;
      int row = e >> 3, colb = e & 7;
      async_cp16((const char*)AOT + ((size_t)(t0 + row) * 512 + k0 + colb * 8) * 2,
                 (char*)dB + e * 16);
    }
  };

  stage(0, 0);
  __syncthreads();
  for (int it = 0; it < 8; ++it) {
    int cur = it & 1;
    if (it < 7) stage(cur ^ 1, (it + 1) * 64);
    const f16* sA = smem + cur * 12288;
    const f16* sB = sA + 4096;
    for (int f = 0; f < 2; ++f) {
      half8 a[2], bfr[4];
      for (int ms = 0; ms < 2; ++ms)
        a[ms] = *(const half8*)&sA[(msub + ms * 16 + l16) * 64 + f * 32 + quad * 8];
      for (int ns = 0; ns < 4; ++ns)
        bfr[ns] = *(const half8*)&sB[(nsub + ns * 16 + l16) * 64 + f * 32 + quad * 8];
      for (int ms = 0; ms < 2; ++ms)
        for (int ns = 0; ns < 4; ++ns)
          acc[ms][ns] =
              __builtin_amdgcn_mfma_f32_16x16x32_f16(a[ms], bfr[ns], acc[ms][ns], 0, 0, 0);
    }
    __syncthreads();
  }
  for (int ms = 0; ms < 2; ++ms) {
    int o_row = o0 + msub + ms * 16 + quad * 4;
    for (int ns = 0; ns < 4; ++ns) {
      int t = t0 + nsub + ns * 16 + l16;
      int b = t / 576, hw = t % 576;
      for (int r = 0; r < 4; ++r) {
        int orow = o_row + r;
        out[(size_t)b * 294912 + (size_t)orow * 576 + hw] = acc[ms][ns][r] + bias[orow];
      }
    }
  }
}

extern "C" void kernel_launch(void* const* d_in, const int* in_sizes, int n_in,
                              void* d_out, int out_size, void* d_ws, size_t ws_size,
                              hipStream_t stream) {
  const float* x = (const float*)d_in[0];
  const float* wqkv = (const float*)d_in[1];
  const float* wproj = (const float*)d_in[2];
  const float* bias = (const float*)d_in[3];
  float* out = (float*)d_out;
  char* ws = (char*)d_ws;
  f16* XT = (f16*)(ws + 0);          // 4,718,592
  f16* WQ = (f16*)(ws + 4718592);    // 1,572,864
  f16* WP = (f16*)(ws + 6291456);    //   524,288
  f16* Qh = (f16*)(ws + 6815744);    // 4,718,592
  f16* Kh = (f16*)(ws + 11534336);   // 4,718,592
  f16* Vh = (f16*)(ws + 16252928);   // 4,718,592  ([gh][d][n'] key-interleaved)
  f16* AOT = (f16*)(ws + 20971520);  // 4,718,592

  k_prep<<<dim3(704), dim3(256), 0, stream>>>(x, XT, wqkv, wproj, WQ, WP);
  k_qkv_gemm<<<dim3(36, 12), dim3(256), 0, stream>>>(XT, WQ, Qh, Kh, Vh);
  k_attn<<<dim3(48, 16), dim3(384), 0, stream>>>(Qh, Kh, Vh, AOT);
  k_proj_gemm<<<dim3(8, 36), dim3(256), 0, stream>>>(AOT, WP, bias, out);
}

// Round 12
// 138.627 us; speedup vs baseline: 1.3840x; 1.0209x over previous
//
#include <hip/hip_runtime.h>
#include <stdint.h>

typedef _Float16 f16;
typedef _Float16 half8 __attribute__((ext_vector_type(8)));
typedef _Float16 half4 __attribute__((ext_vector_type(4)));
typedef _Float16 half2 __attribute__((ext_vector_type(2)));
typedef float floatx4 __attribute__((ext_vector_type(4)));

#define LOG2E 1.44269504088896340736f

// async global->LDS, 16B per lane. LDS dest must be wave-uniform base + lane*16.
__device__ __forceinline__ void async_cp16(const void* g, void* l) {
  __builtin_amdgcn_global_load_lds((const __attribute__((address_space(1))) void*)g,
                                   (__attribute__((address_space(3))) void*)l, 16, 0, 0);
}

// cvt_pkrtz returns __fp16x2; bit-cast to our _Float16-based half2.
__device__ __forceinline__ half2 pkrtz(float a, float b) {
  return __builtin_bit_cast(half2, __builtin_amdgcn_cvt_pkrtz(a, b));
}

// ---------------- fused prep: x transpose->fp16 + weight convert ----------------
__global__ __launch_bounds__(256) void k_prep(const float* __restrict__ x,
                                              f16* __restrict__ XT,
                                              const float* __restrict__ wqkv,
                                              const float* __restrict__ wproj,
                                              f16* __restrict__ WQ, f16* __restrict__ WP) {
  __shared__ f16 sT[64][72];
  const int bid = blockIdx.x;
  const int tid = threadIdx.x;
  if (bid < 576) {
    const int hw0 = (bid % 9) * 64, c0 = ((bid / 9) & 7) * 64, b = bid / 72;
    const int cc = tid >> 6, hwc = tid & 63;
    const float* xb = x + (size_t)b * 294912;
    for (int i = 0; i < 16; ++i) {
      int c = c0 + i * 4 + cc;
      sT[hwc][i * 4 + cc] = (f16)xb[c * 576 + hw0 + hwc];
    }
    __syncthreads();
    const int c_c = tid & 63, rr = tid >> 6;
    f16* xtb = XT + ((size_t)b * 576 + hw0) * 512 + c0;
    for (int j = 0; j < 16; ++j) {
      int r = j * 4 + rr;
      xtb[(size_t)r * 512 + c_c] = sT[r][c_c];
    }
  } else {
    const float SCALE_Q = 0.125f * LOG2E;
    const int total1 = 1536 * 512, total2 = 512 * 512;
    for (int idx = (bid - 576) * 256 + tid; idx < total1 + total2; idx += 128 * 256) {
      if (idx < total1) {
        int row = idx >> 9;
        float v = wqkv[idx];
        if ((row % 192) < 64) v *= SCALE_Q;
        WQ[idx] = (f16)v;
      } else {
        WP[idx - total1] = (f16)wproj[idx - total1];
      }
    }
  }
}

// ---------------- QKV GEMM: D[t][row] = XT[t][:] . WQ[row][:] ----------------
// Double-buffered k-loop (R11-verified). NEW: vectorized epilogue — acc goes to
// LDS sAcc[row][t] (stride 140 f16: 8-row steps hit 17 mod 32 banks -> phase-2
// conflict-free), then Q/K halves are written as coalesced half8 rows (8 lanes =
// one 128B row) instead of 64 scalar f16 scatter-stores per thread. V half uses
// the same buffer with the KEY-INTERLEAVED permutation p = 2*(k&15) | (k>>4)
// (consumed by k_attn's PV 16x16x32; verified R6-R11).
__global__ __launch_bounds__(256) void k_qkv_gemm(const f16* __restrict__ XT,
                                                  const f16* __restrict__ WQ,
                                                  f16* __restrict__ Qh, f16* __restrict__ Kh,
                                                  f16* __restrict__ Vh) {
  const int t0 = blockIdx.x * 128, n0 = blockIdx.y * 128;
  __shared__ alignas(16) f16 smem[2 * 16384];  // 64 KB: [buf][A 8192 | B 8192]
  const int tid = threadIdx.x;
  const int wave = tid >> 6, lane = tid & 63, quad = lane >> 4, l16 = lane & 15;
  const int msub = (wave & 1) * 64, nsub = (wave >> 1) * 64;
  const floatx4 fzero = {0.f, 0.f, 0.f, 0.f};
  floatx4 acc[4][4];
  for (int i = 0; i < 4; ++i)
    for (int j = 0; j < 4; ++j) acc[i][j] = fzero;

  auto stage = [&](int buf, int k0) {
    f16* dA = smem + buf * 16384;
    f16* dB = dA + 8192;
#pragma unroll
    for (int p = 0; p < 4; ++p) {
      int e = p * 256 + tid;
      int row = e >> 3, colb = e & 7;
      async_cp16((const char*)XT + ((size_t)(t0 + row) * 512 + k0 + colb * 8) * 2,
                 (char*)dA + e * 16);
      async_cp16((const char*)WQ + ((size_t)(n0 + row) * 512 + k0 + colb * 8) * 2,
                 (char*)dB + e * 16);
    }
  };

  stage(0, 0);
  __syncthreads();
  for (int it = 0; it < 8; ++it) {
    int cur = it & 1;
    if (it < 7) stage(cur ^ 1, (it + 1) * 64);
    const f16* sA = smem + cur * 16384;
    const f16* sB = sA + 8192;
    for (int f = 0; f < 2; ++f) {
      half8 a[4], bfr[4];
      for (int ms = 0; ms < 4; ++ms)
        a[ms] = *(const half8*)&sA[(msub + ms * 16 + l16) * 64 + f * 32 + quad * 8];
      for (int ns = 0; ns < 4; ++ns)
        bfr[ns] = *(const half8*)&sB[(nsub + ns * 16 + l16) * 64 + f * 32 + quad * 8];
      for (int ms = 0; ms < 4; ++ms)
        for (int ns = 0; ns < 4; ++ns)
          acc[ms][ns] =
              __builtin_amdgcn_mfma_f32_16x16x32_f16(a[ms], bfr[ns], acc[ms][ns], 0, 0, 0);
    }
    __syncthreads();
  }

  // ---- phase 1: all acc -> sAcc[row][t], stride 140 f16 (35840 B of 64 KB) ----
  f16* sAcc = smem;
  for (int ms = 0; ms < 4; ++ms) {
    int tl = msub + ms * 16 + quad * 4;
    for (int ns = 0; ns < 4; ++ns) {
      int row = nsub + ns * 16 + l16;
      half4 hv;
      for (int r = 0; r < 4; ++r) hv[r] = (f16)acc[ms][ns][r];
      *(half4*)&sAcc[row * 140 + tl] = hv;
    }
  }
  __syncthreads();

  // ---- phase 2: per 64-row half, coalesced global stores ----
  for (int hsel = 0; hsel < 2; ++hsel) {
    int nrow = n0 + hsel * 64;
    int h = nrow / 192, sel = (nrow % 192) >> 6;  // 0=Q 1=K 2=V
    const f16* sH = sAcc + hsel * 64 * 140;
    if (sel < 2) {
      f16* dst = sel ? Kh : Qh;
      // 1024 units = 128 t x 8 dchunk; lanes cover dchunk fastest (one 128B row / 8 lanes)
#pragma unroll
      for (int p = 0; p < 4; ++p) {
        int unit = p * 256 + tid;
        int t_l = unit >> 3, dc = unit & 7;
        int t = t0 + t_l;
        int b = t / 576, hw = t - b * 576;
        int gh = (b >> 2) * 8 + h, n = (b & 3) * 576 + hw;
        half8 w;
#pragma unroll
        for (int i = 0; i < 8; ++i) w[i] = sH[(dc * 8 + i) * 140 + t_l];
        *(half8*)(dst + ((size_t)gh * 2304 + n) * 64 + dc * 8) = w;
      }
    } else {
      // V: key-interleaved write (32-token groups; 576%32==0 -> no b-straddle)
#pragma unroll
      for (int p = 0; p < 4; ++p) {
        int unit = p * 256 + tid;  // d*16 + gq*4 + u
        int d = unit >> 4, gq = (unit >> 2) & 3, u = unit & 3;
        int t = t0 + gq * 32;
        int b = t / 576, hw = t - b * 576;
        int gh = (b >> 2) * 8 + h, nb = (b & 3) * 576 + hw;
        half4 va = *(const half4*)&sH[d * 140 + gq * 32 + u * 4];
        half4 vb2 = *(const half4*)&sH[d * 140 + gq * 32 + 16 + u * 4];
        half8 w = __builtin_shufflevector(va, vb2, 0, 4, 1, 5, 2, 6, 3, 7);
        *(half8*)(Vh + (size_t)gh * 147456 + (size_t)d * 2304 + nb + u * 8) = w;
      }
    }
  }
}

// ---------------- flash attention: R9-verified design, unchanged ----------------
// 48 queries/block, 6 waves, key-split 2-way; grid 768 = exactly 3/CU.
// K LDS-staged swizzled; V LDS-staged interleaved; PV one mfma 16x16x32 per dt.
// (R6/R7/R10 established: vector global loads in this loop => ~91 us. Staged only.)
__global__ __launch_bounds__(384, 4) void k_attn(const f16* __restrict__ Qh,
                                                 const f16* __restrict__ Kh,
                                                 const f16* __restrict__ Vh,
                                                 f16* __restrict__ AOT) {
  const int mt = blockIdx.x, gh = blockIdx.y;
  const int m0 = mt * 48;
  const int g = gh >> 3, h = gh & 7;
  const f16* Qg = Qh + (size_t)gh * 147456;  // [n][d]
  const f16* Kg = Kh + (size_t)gh * 147456;  // [n][d]
  const f16* Vg = Vh + (size_t)gh * 147456;  // [d][n'] key-interleaved
  __shared__ alignas(16) f16 smem[16384];    // 32 KB
  f16* sK = smem;                            // [str 2][buf 2][32*64]
  f16* sV = smem + 8192;                     // [str 2][buf 2][64*32]
  const int tid = threadIdx.x;
  const int wave = tid >> 6, lane = tid & 63, quad = lane >> 4, l16 = lane & 15;
  const int str = wave & 1, qgrp = wave >> 1;
  const floatx4 fzero = {0.f, 0.f, 0.f, 0.f};
  const int sw = l16 & 7;
  const int vsw = (l16 >> 1) & 3;
  const half2 one2 = {(f16)1.f, (f16)1.f};

  auto stage_kv = [&](int ktile, int buf) {
#pragma unroll
    for (int p = 0; p < 3; ++p) {
      int idx = p * 384 + tid;
      if (idx < 1024) {
        int isV = idx >= 512;
        int rem = idx & 511;
        int st = rem >> 8, unit = rem & 255;
        if (!isV) {
          int row = unit >> 3, cb = unit & 7;
          async_cp16(
              Kg + (size_t)(st * 1152 + ktile * 32 + row) * 64 + ((cb ^ (row & 7)) << 3),
              (char*)(sK + (st * 2 + buf) * 2048) + unit * 16);
        } else {
          int row = unit >> 2, pc = unit & 3;
          async_cp16(Vg + (size_t)row * 2304 + st * 1152 + ktile * 32 +
                         ((pc ^ ((row >> 1) & 3)) << 3),
                     (char*)(sV + (st * 2 + buf) * 2048) + unit * 16);
        }
      }
    }
  };

  half8 qa[2];
  {
    int qrow = m0 + qgrp * 16 + l16;
    qa[0] = *(const half8*)(Qg + (size_t)qrow * 64 + quad * 8);
    qa[1] = *(const half8*)(Qg + (size_t)qrow * 64 + 32 + quad * 8);
  }

  stage_kv(0, 0);
  __syncthreads();
  stage_kv(1, 1);

  float l_lane = 0.f;
  floatx4 o[4];
  for (int dt = 0; dt < 4; ++dt) o[dt] = fzero;

  for (int kt = 0; kt < 36; ++kt) {
    const f16* bK = sK + (str * 2 + (kt & 1)) * 2048;
    const f16* bV = sV + (str * 2 + (kt & 1)) * 2048;

    half8 vb[4];
#pragma unroll
    for (int dt = 0; dt < 4; ++dt)
      vb[dt] = *(const half8*)&bV[(dt * 16 + l16) * 32 + ((quad ^ vsw) << 3)];

    floatx4 ta, tb;
    {
      half8 k0 = *(const half8*)&bK[l16 * 64 + ((quad ^ sw) << 3)];
      half8 k1 = *(const half8*)&bK[l16 * 64 + (((4 + quad) ^ sw) << 3)];
      ta = __builtin_amdgcn_mfma_f32_16x16x32_f16(k0, qa[0], fzero, 0, 0, 0);
      ta = __builtin_amdgcn_mfma_f32_16x16x32_f16(k1, qa[1], ta, 0, 0, 0);
    }
    {
      half8 k0 = *(const half8*)&bK[(16 + l16) * 64 + ((quad ^ sw) << 3)];
      half8 k1 = *(const half8*)&bK[(16 + l16) * 64 + (((4 + quad) ^ sw) << 3)];
      tb = __builtin_amdgcn_mfma_f32_16x16x32_f16(k0, qa[0], fzero, 0, 0, 0);
      tb = __builtin_amdgcn_mfma_f32_16x16x32_f16(k1, qa[1], tb, 0, 0, 0);
    }
    half2 a0 = pkrtz(__builtin_amdgcn_exp2f(ta[0]), __builtin_amdgcn_exp2f(ta[1]));
    half2 a1 = pkrtz(__builtin_amdgcn_exp2f(ta[2]), __builtin_amdgcn_exp2f(ta[3]));
    half2 b0 = pkrtz(__builtin_amdgcn_exp2f(tb[0]), __builtin_amdgcn_exp2f(tb[1]));
    half2 b1 = pkrtz(__builtin_amdgcn_exp2f(tb[2]), __builtin_amdgcn_exp2f(tb[3]));
    l_lane = __builtin_amdgcn_fdot2(a0, one2, l_lane, false);
    l_lane = __builtin_amdgcn_fdot2(a1, one2, l_lane, false);
    l_lane = __builtin_amdgcn_fdot2(b0, one2, l_lane, false);
    l_lane = __builtin_amdgcn_fdot2(b1, one2, l_lane, false);
    half4 pa = __builtin_shufflevector(a0, a1, 0, 1, 2, 3);
    half4 pb = __builtin_shufflevector(b0, b1, 0, 1, 2, 3);
    half8 pf = __builtin_shufflevector(pa, pb, 0, 4, 1, 5, 2, 6, 3, 7);

#pragma unroll
    for (int dt = 0; dt < 4; ++dt)
      o[dt] = __builtin_amdgcn_mfma_f32_16x16x32_f16(pf, vb[dt], o[dt], 0, 0, 0);

    if (kt < 35) {
      __syncthreads();
      if (kt + 2 < 36) stage_kv(kt + 2, kt & 1);
    }
  }

  __syncthreads();
  float* cO = (float*)smem;                   // [qgrp][dt][lane][4]
  float* cL = (float*)((char*)smem + 24576);  // [qgrp][lane]
  if (str == 1) {
    cL[qgrp * 64 + lane] = l_lane;
#pragma unroll
    for (int dt = 0; dt < 4; ++dt)
      *(floatx4*)&cO[((qgrp * 4 + dt) * 64 + lane) * 4] = o[dt];
  }
  __syncthreads();
  if (str == 0) {
    l_lane += cL[qgrp * 64 + lane];
#pragma unroll
    for (int dt = 0; dt < 4; ++dt)
      o[dt] += *(const floatx4*)&cO[((qgrp * 4 + dt) * 64 + lane) * 4];

    l_lane += __shfl_xor(l_lane, 16, 64);
    l_lane += __shfl_xor(l_lane, 32, 64);
    float inv[4];
#pragma unroll
    for (int r = 0; r < 4; ++r) {
      float lr = __shfl(l_lane, quad * 4 + r, 64);
      inv[r] = 1.f / lr;
    }
#pragma unroll
    for (int dt = 0; dt < 4; ++dt)
#pragma unroll
      for (int r = 0; r < 4; ++r) {
        int n_tok = m0 + qgrp * 16 + quad * 4 + r;
        int v = n_tok / 576, hw = n_tok % 576;
        int bb = g * 4 + v;
        int c = h * 64 + dt * 16 + l16;
        AOT[((size_t)bb * 576 + hw) * 512 + c] = (f16)(o[dt][r] * inv[r]);
      }
  }
}

// ---------------- proj GEMM: 64(o) x 128(t) tiles, double-buffered k-loop ----------
__global__ __launch_bounds__(256) void k_proj_gemm(const f16* __restrict__ AOT,
                                                   const f16* __restrict__ WP,
                                                   const float* __restrict__ bias,
                                                   float* __restrict__ out) {
  const int o0 = blockIdx.x * 64, t0 = blockIdx.y * 128;
  __shared__ alignas(16) f16 smem[2 * 12288];  // 48 KB: [buf][A 4096 | B 8192]
  const int tid = threadIdx.x;
  const int wave = tid >> 6, lane = tid & 63, quad = lane >> 4, l16 = lane & 15;
  const int msub = (wave & 1) * 32, nsub = (wave >> 1) * 64;
  const floatx4 fzero = {0.f, 0.f, 0.f, 0.f};
  floatx4 acc[2][4];
  for (int i = 0; i < 2; ++i)
    for (int j = 0; j < 4; ++j) acc[i][j] = fzero;

  auto stage = [&](int buf, int k0) {
    f16* dA = smem + buf * 12288;
    f16* dB = dA + 4096;
#pragma unroll
    for (int p = 0; p < 2; ++p) {
      int e = p * 256 + tid;
      int row = e >> 3, colb = e & 7;
      async_cp16((const char*)WP + ((size_t)(o0 + row) * 512 + k0 + colb * 8) * 2,
                 (char*)dA + e * 16);
    }
#pragma unroll
    for (int p = 0; p < 4; ++p) {
      int e = p * 256 + tid;
      int row = e >> 3, colb = e & 7;
      async_cp16((const char*)AOT + ((size_t)(t0 + row) * 512 + k0 + colb * 8) * 2,
                 (char*)dB + e * 16);
    }
  };

  stage(0, 0);
  __syncthreads();
  for (int it = 0; it < 8; ++it) {
    int cur = it & 1;
    if (it < 7) stage(cur ^ 1, (it + 1) * 64);
    const f16* sA = smem + cur * 12288;
    const f16* sB = sA + 4096;
    for (int f = 0; f < 2; ++f) {
      half8 a[2], bfr[4];
      for (int ms = 0; ms < 2; ++ms)
        a[ms] = *(const half8*)&sA[(msub + ms * 16 + l16) * 64 + f * 32 + quad * 8];
      for (int ns = 0; ns < 4; ++ns)
        bfr[ns] = *(const half8*)&sB[(nsub + ns * 16 + l16) * 64 + f * 32 + quad * 8];
      for (int ms = 0; ms < 2; ++ms)
        for (int ns = 0; ns < 4; ++ns)
          acc[ms][ns] =
              __builtin_amdgcn_mfma_f32_16x16x32_f16(a[ms], bfr[ns], acc[ms][ns], 0, 0, 0);
    }
    __syncthreads();
  }
  for (int ms = 0; ms < 2; ++ms) {
    int o_row = o0 + msub + ms * 16 + quad * 4;
    for (int ns = 0; ns < 4; ++ns) {
      int t = t0 + nsub + ns * 16 + l16;
      int b = t / 576, hw = t % 576;
      for (int r = 0; r < 4; ++r) {
        int orow = o_row + r;
        out[(size_t)b * 294912 + (size_t)orow * 576 + hw] = acc[ms][ns][r] + bias[orow];
      }
    }
  }
}

extern "C" void kernel_launch(void* const* d_in, const int* in_sizes, int n_in,
                              void* d_out, int out_size, void* d_ws, size_t ws_size,
                              hipStream_t stream) {
  const float* x = (const float*)d_in[0];
  const float* wqkv = (const float*)d_in[1];
  const float* wproj = (const float*)d_in[2];
  const float* bias = (const float*)d_in[3];
  float* out = (float*)d_out;
  char* ws = (char*)d_ws;
  f16* XT = (f16*)(ws + 0);          // 4,718,592
  f16* WQ = (f16*)(ws + 4718592);    // 1,572,864
  f16* WP = (f16*)(ws + 6291456);    //   524,288
  f16* Qh = (f16*)(ws + 6815744);    // 4,718,592
  f16* Kh = (f16*)(ws + 11534336);   // 4,718,592
  f16* Vh = (f16*)(ws + 16252928);   // 4,718,592  ([gh][d][n'] key-interleaved)
  f16* AOT = (f16*)(ws + 20971520);  // 4,718,592

  k_prep<<<dim3(704), dim3(256), 0, stream>>>(x, XT, wqkv, wproj, WQ, WP);
  k_qkv_gemm<<<dim3(36, 12), dim3(256), 0, stream>>>(XT, WQ, Qh, Kh, Vh);
  k_attn<<<dim3(48, 16), dim3(384), 0, stream>>>(Qh, Kh, Vh, AOT);
  k_proj_gemm<<<dim3(8, 36), dim3(256), 0, stream>>>(AOT, WP, bias, out);
}